// Round 1
// baseline (8977.320 us; speedup 1.0000x reference)
//
#include <hip/hip_runtime.h>

#define B_SZ 128
#define T_SZ 512
#define D_SZ 128
#define H_SZ 512

// in[R][C] -> out[C][R], R,C multiples of 32
__global__ __launch_bounds__(256) void transpose_k(const float* __restrict__ in,
                                                   float* __restrict__ out,
                                                   int R, int C) {
  __shared__ float tile[32][33];
  int c0 = blockIdx.x * 32, r0 = blockIdx.y * 32;
  int tx = threadIdx.x & 31, ty = threadIdx.x >> 5;  // 32 x 8
  for (int i = ty; i < 32; i += 8)
    tile[i][tx] = in[(size_t)(r0 + i) * C + (c0 + tx)];
  __syncthreads();
  for (int i = ty; i < 32; i += 8)
    out[(size_t)(c0 + i) * R + (r0 + tx)] = tile[tx][i];
}

// x_in = x @ W_in^T + b   ([BT,128] x [128,512] -> [BT,512])
// Block: 256 threads, 32 rows x 512 cols per block.
__global__ __launch_bounds__(256) void input_proj_k(
    const float* __restrict__ x,     // [BT][128]
    const float* __restrict__ WTin,  // [128][512] (transposed W_in)
    const float* __restrict__ bias,  // [512]
    float* __restrict__ out)         // [BT][512]
{
  __shared__ float xs[32 * 128];  // 16 KB
  const int tid = threadIdx.x;
  const size_t r0 = (size_t)blockIdx.x * 32;

  // stage x tile (coalesced float4)
  const float4* xg = (const float4*)(x + r0 * D_SZ);
  float4* xs4s = (float4*)xs;
#pragma unroll
  for (int i = 0; i < 4; ++i) xs4s[tid + i * 256] = xg[tid + i * 256];
  __syncthreads();

  const int q = tid & 127;  // float4 column index (cols 4q..4q+3)
  const int rg = tid >> 7;  // row group 0/1 (rows rg*16 .. +15)
  const float4* W4 = (const float4*)WTin;      // [128][128] float4
  const float4* xs4 = (const float4*)xs;       // [32][32] float4

  float acc[16][4];
#pragma unroll
  for (int r = 0; r < 16; ++r)
#pragma unroll
    for (int c = 0; c < 4; ++c) acc[r][c] = 0.f;

  for (int k4 = 0; k4 < 32; ++k4) {
    float w[4][4];
#pragma unroll
    for (int kk = 0; kk < 4; ++kk) {
      float4 wv = W4[(size_t)(k4 * 4 + kk) * 128 + q];
      w[kk][0] = wv.x; w[kk][1] = wv.y; w[kk][2] = wv.z; w[kk][3] = wv.w;
    }
#pragma unroll
    for (int r = 0; r < 16; ++r) {
      float4 xv = xs4[(rg * 16 + r) * 32 + k4];
      float xk[4] = {xv.x, xv.y, xv.z, xv.w};
#pragma unroll
      for (int kk = 0; kk < 4; ++kk) {
#pragma unroll
        for (int c = 0; c < 4; ++c)
          acc[r][c] = fmaf(xk[kk], w[kk][c], acc[r][c]);
      }
    }
  }

  float4 bv = ((const float4*)bias)[q];
  float bb[4] = {bv.x, bv.y, bv.z, bv.w};
#pragma unroll
  for (int r = 0; r < 16; ++r) {
    float4 o;
    o.x = acc[r][0] + bb[0];
    o.y = acc[r][1] + bb[1];
    o.z = acc[r][2] + bb[2];
    o.w = acc[r][3] + bb[3];
    ((float4*)(out + (r0 + rg * 16 + r) * H_SZ))[q] = o;
  }
}

// Recurrence: one block per 2 batch rows. seq holds x_in on entry; we
// overwrite seq[b,t,:] with h_t in place (each slot read once, then written).
__global__ __launch_bounds__(256) void ltc_rec_k(
    float* __restrict__ seq,        // [B][T][H], in: x_in, out: h_seq
    float* __restrict__ h_last,     // [B][H]
    const float* __restrict__ hin,  // [B][H] initial h
    const float* __restrict__ tau,  // [B]
    const float* __restrict__ WT)   // [512][512] = W_rec^T (WT[k][j] = W_rec[j][k])
{
  __shared__ float2 hs[H_SZ];  // hs[k] = {h_b0[k], h_b1[k]}
  const int t = threadIdx.x;   // 0..255
  const int b0 = blockIdx.x * 2, b1 = b0 + 1;
  const float it0 = 1.0f / tau[b0];
  const float it1 = 1.0f / tau[b1];
  const int j0 = 2 * t;  // this thread owns cols j0, j0+1

  float2 h0v = *(const float2*)&hin[(size_t)b0 * H_SZ + j0];
  float2 h1v = *(const float2*)&hin[(size_t)b1 * H_SZ + j0];
  hs[j0]     = make_float2(h0v.x, h1v.x);
  hs[j0 + 1] = make_float2(h0v.y, h1v.y);
  __syncthreads();

  const float2* W2 = (const float2*)WT;  // [512][256] float2
  float* p0 = seq + (size_t)b0 * T_SZ * H_SZ + j0;
  float* p1 = seq + (size_t)b1 * T_SZ * H_SZ + j0;

  for (int s = 0; s < T_SZ; ++s) {
    float a00 = 0.f, a01 = 0.f, a10 = 0.f, a11 = 0.f;
#pragma unroll 32
    for (int k = 0; k < H_SZ; ++k) {
      float2 w = W2[(size_t)k * 256 + t];
      float2 hh = hs[k];
      a00 = fmaf(hh.x, w.x, a00);
      a01 = fmaf(hh.x, w.y, a01);
      a10 = fmaf(hh.y, w.x, a10);
      a11 = fmaf(hh.y, w.y, a11);
    }
    float2 x0 = *(const float2*)p0;
    float2 x1 = *(const float2*)p1;
    float u00 = tanhf(x0.x + a00), u01 = tanhf(x0.y + a01);
    float u10 = tanhf(x1.x + a10), u11 = tanhf(x1.y + a11);
    float n00 = fmaf(u00 - h0v.x, it0, h0v.x);
    float n01 = fmaf(u01 - h0v.y, it0, h0v.y);
    float n10 = fmaf(u10 - h1v.x, it1, h1v.x);
    float n11 = fmaf(u11 - h1v.y, it1, h1v.y);
    h0v = make_float2(n00, n01);
    h1v = make_float2(n10, n11);
    *(float2*)p0 = h0v;
    *(float2*)p1 = h1v;
    p0 += H_SZ;
    p1 += H_SZ;
    __syncthreads();  // all K-loop reads of hs for step s are done
    hs[j0]     = make_float2(n00, n10);
    hs[j0 + 1] = make_float2(n01, n11);
    __syncthreads();  // new h visible to all
  }

  // h_last
  *(float2*)&h_last[(size_t)b0 * H_SZ + j0] = h0v;
  *(float2*)&h_last[(size_t)b1 * H_SZ + j0] = h1v;
}

extern "C" void kernel_launch(void* const* d_in, const int* in_sizes, int n_in,
                              void* d_out, int out_size, void* d_ws, size_t ws_size,
                              hipStream_t stream) {
  const float* x     = (const float*)d_in[0];
  const float* hin   = (const float*)d_in[1];
  const float* tau   = (const float*)d_in[2];
  const float* Win_w = (const float*)d_in[3];  // [512][128]
  const float* Win_b = (const float*)d_in[4];  // [512]
  const float* Wrec  = (const float*)d_in[5];  // [512][512]

  float* out    = (float*)d_out;
  float* seq    = out;                                   // [B][T][H]
  float* h_last = out + (size_t)B_SZ * T_SZ * H_SZ;      // [B][H]

  float* WTin  = (float*)d_ws;            // [128][512] f32 = 256 KB
  float* WTrec = WTin + D_SZ * H_SZ;      // [512][512] f32 = 1 MB

  dim3 blk(256);
  // W_in [512][128] -> WTin [128][512]
  transpose_k<<<dim3(D_SZ / 32, H_SZ / 32), blk, 0, stream>>>(Win_w, WTin, H_SZ, D_SZ);
  // W_rec [512][512] -> WTrec [512][512]
  transpose_k<<<dim3(H_SZ / 32, H_SZ / 32), blk, 0, stream>>>(Wrec, WTrec, H_SZ, H_SZ);
  // x_in -> seq (in-place staging inside d_out)
  input_proj_k<<<(B_SZ * T_SZ) / 32, blk, 0, stream>>>(x, WTin, Win_b, seq);
  // serial scan, 2 batch rows per block
  ltc_rec_k<<<B_SZ / 2, blk, 0, stream>>>(seq, h_last, hin, tau, WTrec);
}

// Round 2
// 4495.793 us; speedup vs baseline: 1.9968x; 1.9968x over previous
//
#include <hip/hip_runtime.h>

#define B_SZ 128
#define T_SZ 512
#define D_SZ 128
#define H_SZ 512

#define NG 8    // batch groups
#define GB 16   // batch rows per group
#define NS 4    // column slices (blocks per group)
#define SN 128  // columns per slice

typedef _Float16 f16;
typedef _Float16 f16x8 __attribute__((ext_vector_type(8)));
typedef _Float16 f16x4 __attribute__((ext_vector_type(4)));
typedef float f32x4 __attribute__((ext_vector_type(4)));

// ---------------- W_in transpose (for input projection) ----------------
__global__ __launch_bounds__(256) void transpose_k(const float* __restrict__ in,
                                                   float* __restrict__ out,
                                                   int R, int C) {
  __shared__ float tile[32][33];
  int c0 = blockIdx.x * 32, r0 = blockIdx.y * 32;
  int tx = threadIdx.x & 31, ty = threadIdx.x >> 5;
  for (int i = ty; i < 32; i += 8)
    tile[i][tx] = in[(size_t)(r0 + i) * C + (c0 + tx)];
  __syncthreads();
  for (int i = ty; i < 32; i += 8)
    out[(size_t)(c0 + i) * R + (r0 + tx)] = tile[tx][i];
}

// ---------------- x_in = x @ W_in^T + b ----------------
__global__ __launch_bounds__(256) void input_proj_k(
    const float* __restrict__ x,     // [BT][128]
    const float* __restrict__ WTin,  // [128][512]
    const float* __restrict__ bias,  // [512]
    float* __restrict__ out)         // [BT][512]
{
  __shared__ float xs[32 * 128];
  const int tid = threadIdx.x;
  const size_t r0 = (size_t)blockIdx.x * 32;

  const float4* xg = (const float4*)(x + r0 * D_SZ);
  float4* xs4s = (float4*)xs;
#pragma unroll
  for (int i = 0; i < 4; ++i) xs4s[tid + i * 256] = xg[tid + i * 256];
  __syncthreads();

  const int q = tid & 127;
  const int rg = tid >> 7;
  const float4* W4 = (const float4*)WTin;
  const float4* xs4 = (const float4*)xs;

  float acc[16][4];
#pragma unroll
  for (int r = 0; r < 16; ++r)
#pragma unroll
    for (int c = 0; c < 4; ++c) acc[r][c] = 0.f;

  for (int k4 = 0; k4 < 32; ++k4) {
    float w[4][4];
#pragma unroll
    for (int kk = 0; kk < 4; ++kk) {
      float4 wv = W4[(size_t)(k4 * 4 + kk) * 128 + q];
      w[kk][0] = wv.x; w[kk][1] = wv.y; w[kk][2] = wv.z; w[kk][3] = wv.w;
    }
#pragma unroll
    for (int r = 0; r < 16; ++r) {
      float4 xv = xs4[(rg * 16 + r) * 32 + k4];
      float xk[4] = {xv.x, xv.y, xv.z, xv.w};
#pragma unroll
      for (int kk = 0; kk < 4; ++kk)
#pragma unroll
        for (int c = 0; c < 4; ++c)
          acc[r][c] = fmaf(xk[kk], w[kk][c], acc[r][c]);
    }
  }

  float4 bv = ((const float4*)bias)[q];
  float bb[4] = {bv.x, bv.y, bv.z, bv.w};
#pragma unroll
  for (int r = 0; r < 16; ++r) {
    float4 o;
    o.x = acc[r][0] + bb[0];
    o.y = acc[r][1] + bb[1];
    o.z = acc[r][2] + bb[2];
    o.w = acc[r][3] + bb[3];
    ((float4*)(out + (r0 + rg * 16 + r) * H_SZ))[q] = o;
  }
}

// ---------------- recurrence: MFMA, W-in-registers, 4-way column split ----
// Block (slice,g): computes h[:, slice*128..+128] for batches g*16..+16.
// seq holds x_in on entry; each [b,t,j] slot is read once (x_in) then
// overwritten with h_t — and doubles as the inter-block h exchange buffer.
// cnt[g*T+s]: per-group per-step arrival counter (release/acquire).
__global__ __launch_bounds__(512) void ltc_rec_mfma(
    float* __restrict__ seq,        // [B][T][H]
    float* __restrict__ h_last,     // [B][H]
    const float* __restrict__ hin,  // [B][H]
    const float* __restrict__ tau,  // [B]
    const float* __restrict__ Wrec, // [H][H] row-major (W_rec[j][k])
    int* __restrict__ cnt)          // [NG][T]
{
  __shared__ f16 hs[GB * H_SZ];  // [16][512] f16, XOR-swizzled, 16 KB

  const int tid = threadIdx.x;
  const int g = blockIdx.x & 7;
  const int slice = blockIdx.x >> 3;
  const int w = tid >> 6;   // wave 0..7
  const int l = tid & 63;
  const int m = l & 15;     // batch-in-group (MFMA col)
  const int kg = l >> 4;    // 0..3
  const int jt = slice * SN + w * 16;  // wave's j-tile base (global col)
  const int j0 = jt + kg * 4;          // this lane's 4 output cols
  const int b = g * GB + m;            // global batch row

  // ---- one-time: A-fragments = W_rec rows (f16), 64 VGPRs ----
  f16x8 afrag[16];
  {
    const float* wr = Wrec + (size_t)(jt + m) * H_SZ;
#pragma unroll
    for (int f = 0; f < 16; ++f) {
      const int k0 = f * 32 + kg * 8;
      float4 u0 = *(const float4*)(wr + k0);
      float4 u1 = *(const float4*)(wr + k0 + 4);
      f16x8 a;
      a[0] = (f16)u0.x; a[1] = (f16)u0.y; a[2] = (f16)u0.z; a[3] = (f16)u0.w;
      a[4] = (f16)u1.x; a[5] = (f16)u1.y; a[6] = (f16)u1.z; a[7] = (f16)u1.w;
      afrag[f] = a;
    }
  }

  // ---- init: h state registers (fp32, persist all steps) ----
  float hreg[4];
  {
    float4 h0 = *(const float4*)(hin + (size_t)b * H_SZ + j0);
    hreg[0] = h0.x; hreg[1] = h0.y; hreg[2] = h0.z; hreg[3] = h0.w;
  }
  const float itau = 1.0f / tau[b];

  // ---- init: full h_0 (all 512 cols) into LDS as f16 ----
  {
    const int mr = tid >> 5;         // 0..15
    const int c4 = (tid & 31) * 4;   // 0..124
#pragma unroll
    for (int p = 0; p < 4; ++p) {
      const int col = p * SN + c4;
      float4 v = *(const float4*)(hin + (size_t)(g * GB + mr) * H_SZ + col);
      const int e = (mr * H_SZ + col) ^ ((mr & 7) << 3);
      f16x4 hf;
      hf[0] = (f16)v.x; hf[1] = (f16)v.y; hf[2] = (f16)v.z; hf[3] = (f16)v.w;
      *(f16x4*)&hs[e] = hf;
    }
  }
  __syncthreads();

  float* seqp = seq + (size_t)b * T_SZ * H_SZ + j0;  // [b][0][j0]
  const int gmr = tid >> 5;                // gather row
  const int gc4 = (tid & 31) * 4;          // gather col-in-slice
  const float* grow = seq + (size_t)(g * GB + gmr) * T_SZ * H_SZ;

  for (int s = 0; s < T_SZ; ++s) {
    // x_in prefetch (own slot, overwritten below)
    float4 xin = *(const float4*)seqp;

    // GEMM tile: acc[j = jt+kg*4+r][m]
    f32x4 acc = {0.f, 0.f, 0.f, 0.f};
#pragma unroll
    for (int f = 0; f < 16; ++f) {
      const int e = (m * H_SZ + f * 32 + kg * 8) ^ ((m & 7) << 3);
      f16x8 bfrag = *(const f16x8*)&hs[e];
      acc = __builtin_amdgcn_mfma_f32_16x16x32_f16(afrag[f], bfrag, acc, 0, 0, 0);
    }

    // epilogue: u = tanh(x_in + rec); h += (u - h)/tau
    float4 hv;
    hv.x = fmaf(tanhf(xin.x + acc[0]) - hreg[0], itau, hreg[0]);
    hv.y = fmaf(tanhf(xin.y + acc[1]) - hreg[1], itau, hreg[1]);
    hv.z = fmaf(tanhf(xin.z + acc[2]) - hreg[2], itau, hreg[2]);
    hv.w = fmaf(tanhf(xin.w + acc[3]) - hreg[3], itau, hreg[3]);
    hreg[0] = hv.x; hreg[1] = hv.y; hreg[2] = hv.z; hreg[3] = hv.w;

    *(float4*)seqp = hv;     // publish own slice (fp32, also the output)
    seqp += H_SZ;
    __threadfence();         // make seq stores device-visible

    __syncthreads();         // all LDS B-frag reads for step s done

    // own slice of h_s into LDS (f16)
    {
      const int e = (m * H_SZ + j0) ^ ((m & 7) << 3);
      f16x4 hf;
      hf[0] = (f16)hv.x; hf[1] = (f16)hv.y; hf[2] = (f16)hv.z; hf[3] = (f16)hv.w;
      *(f16x4*)&hs[e] = hf;
    }

    if (tid == 0) {
      __hip_atomic_fetch_add(&cnt[g * T_SZ + s], 1, __ATOMIC_RELEASE,
                             __HIP_MEMORY_SCOPE_AGENT);
      while (__hip_atomic_load(&cnt[g * T_SZ + s], __ATOMIC_ACQUIRE,
                               __HIP_MEMORY_SCOPE_AGENT) < NS) {}
    }
    __syncthreads();         // peers' h_s now visible

    // gather 3 peer slices of h_s into LDS (f16)
    {
      const float* srow = grow + (size_t)s * H_SZ;
#pragma unroll
      for (int p = 0; p < 3; ++p) {
        const int ps = (slice + 1 + p) & 3;
        const int col = ps * SN + gc4;
        float4 v = *(const float4*)(srow + col);
        const int e = (gmr * H_SZ + col) ^ ((gmr & 7) << 3);
        f16x4 hf;
        hf[0] = (f16)v.x; hf[1] = (f16)v.y; hf[2] = (f16)v.z; hf[3] = (f16)v.w;
        *(f16x4*)&hs[e] = hf;
      }
    }
    __syncthreads();         // LDS h_s complete for step s+1
  }

  float4 hv;
  hv.x = hreg[0]; hv.y = hreg[1]; hv.z = hreg[2]; hv.w = hreg[3];
  *(float4*)(h_last + (size_t)b * H_SZ + j0) = hv;
}

extern "C" void kernel_launch(void* const* d_in, const int* in_sizes, int n_in,
                              void* d_out, int out_size, void* d_ws, size_t ws_size,
                              hipStream_t stream) {
  const float* x     = (const float*)d_in[0];
  const float* hin   = (const float*)d_in[1];
  const float* tau   = (const float*)d_in[2];
  const float* Win_w = (const float*)d_in[3];  // [512][128]
  const float* Win_b = (const float*)d_in[4];  // [512]
  const float* Wrec  = (const float*)d_in[5];  // [512][512]

  float* out    = (float*)d_out;
  float* seq    = out;                               // [B][T][H]
  float* h_last = out + (size_t)B_SZ * T_SZ * H_SZ;  // [B][H]

  int*   cnt  = (int*)d_ws;                          // 8*512*4 = 16 KB
  float* WTin = (float*)((char*)d_ws + NG * T_SZ * sizeof(int));  // 256 KB

  hipMemsetAsync(cnt, 0, NG * T_SZ * sizeof(int), stream);

  dim3 blk(256);
  transpose_k<<<dim3(D_SZ / 32, H_SZ / 32), blk, 0, stream>>>(Win_w, WTin, H_SZ, D_SZ);
  input_proj_k<<<(B_SZ * T_SZ) / 32, blk, 0, stream>>>(x, WTin, Win_b, seq);
  ltc_rec_mfma<<<NG * NS, 512, 0, stream>>>(seq, h_last, hin, tau, Wrec, cnt);
}

// Round 4
// 1236.797 us; speedup vs baseline: 7.2585x; 3.6350x over previous
//
#include <hip/hip_runtime.h>

#define B_SZ 128
#define T_SZ 512
#define D_SZ 128
#define H_SZ 512

#define NG 8    // batch groups
#define GB 16   // batch rows per group
#define NS 4    // column slices (blocks per group)
#define SN 128  // columns per slice

typedef _Float16 f16;
typedef _Float16 f16x8 __attribute__((ext_vector_type(8)));
typedef _Float16 f16x4 __attribute__((ext_vector_type(4)));
typedef float f32x4 __attribute__((ext_vector_type(4)));

// ---------------- W_in transpose ----------------
__global__ __launch_bounds__(256) void transpose_k(const float* __restrict__ in,
                                                   float* __restrict__ out,
                                                   int R, int C) {
  __shared__ float tile[32][33];
  int c0 = blockIdx.x * 32, r0 = blockIdx.y * 32;
  int tx = threadIdx.x & 31, ty = threadIdx.x >> 5;
  for (int i = ty; i < 32; i += 8)
    tile[i][tx] = in[(size_t)(r0 + i) * C + (c0 + tx)];
  __syncthreads();
  for (int i = ty; i < 32; i += 8)
    out[(size_t)(c0 + i) * R + (r0 + tx)] = tile[tx][i];
}

// ---------------- x_in = x @ W_in^T + b ----------------
__global__ __launch_bounds__(256) void input_proj_k(
    const float* __restrict__ x,     // [BT][128]
    const float* __restrict__ WTin,  // [128][512]
    const float* __restrict__ bias,  // [512]
    float* __restrict__ out)         // [BT][512]
{
  __shared__ float xs[32 * 128];
  const int tid = threadIdx.x;
  const size_t r0 = (size_t)blockIdx.x * 32;

  const float4* xg = (const float4*)(x + r0 * D_SZ);
  float4* xs4s = (float4*)xs;
#pragma unroll
  for (int i = 0; i < 4; ++i) xs4s[tid + i * 256] = xg[tid + i * 256];
  __syncthreads();

  const int q = tid & 127;
  const int rg = tid >> 7;
  const float4* W4 = (const float4*)WTin;
  const float4* xs4 = (const float4*)xs;

  float acc[16][4];
#pragma unroll
  for (int r = 0; r < 16; ++r)
#pragma unroll
    for (int c = 0; c < 4; ++c) acc[r][c] = 0.f;

  for (int k4 = 0; k4 < 32; ++k4) {
    float w[4][4];
#pragma unroll
    for (int kk = 0; kk < 4; ++kk) {
      float4 wv = W4[(size_t)(k4 * 4 + kk) * 128 + q];
      w[kk][0] = wv.x; w[kk][1] = wv.y; w[kk][2] = wv.z; w[kk][3] = wv.w;
    }
#pragma unroll
    for (int r = 0; r < 16; ++r) {
      float4 xv = xs4[(rg * 16 + r) * 32 + k4];
      float xk[4] = {xv.x, xv.y, xv.z, xv.w};
#pragma unroll
      for (int kk = 0; kk < 4; ++kk)
#pragma unroll
        for (int c = 0; c < 4; ++c)
          acc[r][c] = fmaf(xk[kk], w[kk][c], acc[r][c]);
    }
  }

  float4 bv = ((const float4*)bias)[q];
  float bb[4] = {bv.x, bv.y, bv.z, bv.w};
#pragma unroll
  for (int r = 0; r < 16; ++r) {
    float4 o;
    o.x = acc[r][0] + bb[0];
    o.y = acc[r][1] + bb[1];
    o.z = acc[r][2] + bb[2];
    o.w = acc[r][3] + bb[3];
    ((float4*)(out + (r0 + rg * 16 + r) * H_SZ))[q] = o;
  }
}

__device__ __forceinline__ float fast_tanh(float y) {
  float e = __expf(2.0f * y);
  return 1.0f - __fdividef(2.0f, e + 1.0f);
}

// ---------------- recurrence ----------------
// Cross-block exchange via relaxed AGENT-scope (sc1, LLC) 8B atomics on a
// depth-2 f16 ring in d_ws. No acquire/release cache maintenance anywhere.
// Handshake: single lane does relaxed fetch_add then relaxed poll of the
// SAME counter (no cross-branch divergent dependency -> no deadlock).
// Manual release: barrier [1]'s implicit vmcnt(0) drains sc1 stores first.
__global__ __launch_bounds__(512) void ltc_rec_mfma(
    float* __restrict__ seq,        // [B][T][H]  in: x_in, out: h_seq
    float* __restrict__ h_last,     // [B][H]
    const float* __restrict__ hin,  // [B][H]
    const float* __restrict__ tau,  // [B]
    const float* __restrict__ Wrec, // [H][H] row-major
    int* __restrict__ cnt,          // [NG][T] arrival counters
    f16* __restrict__ ex)           // [2][NG][NS][GB][SN] exchange ring
{
  __shared__ f16 hs[2][GB * H_SZ];  // double-buffered, XOR-swizzled, 2x16KB

  const int tid = threadIdx.x;
  const int g = blockIdx.x & 7;
  const int slice = blockIdx.x >> 3;
  const int w = tid >> 6;
  const int l = tid & 63;
  const int m = l & 15;            // batch-in-group (MFMA col)
  const int kg = l >> 4;           // 0..3
  const int jt = slice * SN + w * 16;
  const int j0 = jt + kg * 4;
  const int b = g * GB + m;

  // one-time: A-fragments = W_rec rows (f16)
  f16x8 afrag[16];
  {
    const float* wr = Wrec + (size_t)(jt + m) * H_SZ;
#pragma unroll
    for (int f = 0; f < 16; ++f) {
      const int k0 = f * 32 + kg * 8;
      float4 u0 = *(const float4*)(wr + k0);
      float4 u1 = *(const float4*)(wr + k0 + 4);
      f16x8 a;
      a[0] = (f16)u0.x; a[1] = (f16)u0.y; a[2] = (f16)u0.z; a[3] = (f16)u0.w;
      a[4] = (f16)u1.x; a[5] = (f16)u1.y; a[6] = (f16)u1.z; a[7] = (f16)u1.w;
      afrag[f] = a;
    }
  }

  float hreg[4];
  {
    float4 h0 = *(const float4*)(hin + (size_t)b * H_SZ + j0);
    hreg[0] = h0.x; hreg[1] = h0.y; hreg[2] = h0.z; hreg[3] = h0.w;
  }
  const float itau = 1.0f / tau[b];

  // init: full h_0 into hs[0] as f16
  {
    const int mr = tid >> 5;
    const int c4 = (tid & 31) * 4;
#pragma unroll
    for (int p = 0; p < 4; ++p) {
      const int col = p * SN + c4;
      float4 v = *(const float4*)(hin + (size_t)(g * GB + mr) * H_SZ + col);
      const int e = (mr * H_SZ + col) ^ ((mr & 7) << 3);
      f16x4 hf;
      hf[0] = (f16)v.x; hf[1] = (f16)v.y; hf[2] = (f16)v.z; hf[3] = (f16)v.w;
      *(f16x4*)&hs[0][e] = hf;
    }
  }
  __syncthreads();

  const int gmr = tid >> 5;
  const int gc4 = (tid & 31) * 4;

  float* seqp = seq + (size_t)b * T_SZ * H_SZ + j0;
  float4 xin = *(const float4*)seqp;  // step-0 x_in prefetch

  const size_t EXB = (size_t)GB * SN;  // 2048 f16 per (ring,g,slice)

  for (int s = 0; s < T_SZ; ++s) {
    const int cur = s & 1, nxt = cur ^ 1;

    // ---- recurrent GEMM tile: acc[j=j0+r][m] over K=512 ----
    f32x4 acc0 = {0.f, 0.f, 0.f, 0.f};
    f32x4 acc1 = {0.f, 0.f, 0.f, 0.f};
#pragma unroll
    for (int f = 0; f < 8; ++f) {
      const int e = (m * H_SZ + f * 32 + kg * 8) ^ ((m & 7) << 3);
      acc0 = __builtin_amdgcn_mfma_f32_16x16x32_f16(afrag[f], *(const f16x8*)&hs[cur][e], acc0, 0, 0, 0);
    }
#pragma unroll
    for (int f = 8; f < 16; ++f) {
      const int e = (m * H_SZ + f * 32 + kg * 8) ^ ((m & 7) << 3);
      acc1 = __builtin_amdgcn_mfma_f32_16x16x32_f16(afrag[f], *(const f16x8*)&hs[cur][e], acc1, 0, 0, 0);
    }
    f32x4 acc = acc0 + acc1;

    // ---- epilogue ----
    float4 hv;
    hv.x = fmaf(fast_tanh(xin.x + acc[0]) - hreg[0], itau, hreg[0]);
    hv.y = fmaf(fast_tanh(xin.y + acc[1]) - hreg[1], itau, hreg[1]);
    hv.z = fmaf(fast_tanh(xin.z + acc[2]) - hreg[2], itau, hreg[2]);
    hv.w = fmaf(fast_tanh(xin.w + acc[3]) - hreg[3], itau, hreg[3]);
    hreg[0] = hv.x; hreg[1] = hv.y; hreg[2] = hv.z; hreg[3] = hv.w;

    f16x4 hf;
    hf[0] = (f16)hv.x; hf[1] = (f16)hv.y; hf[2] = (f16)hv.z; hf[3] = (f16)hv.w;

    // own slice into next LDS buffer
    {
      const int e = (m * H_SZ + j0) ^ ((m & 7) << 3);
      *(f16x4*)&hs[nxt][e] = hf;
    }
    // output store: plain cached (local L2), never read cross-block
    *(float4*)seqp = hv;
    seqp += H_SZ;
    // exchange publish: relaxed agent (sc1 -> LLC), 8B
    {
      f16* exp_ = ex + ((size_t)(cur * NG + g) * NS + slice) * EXB + m * SN + (w * 16 + kg * 4);
      __hip_atomic_store((unsigned long long*)exp_, __builtin_bit_cast(unsigned long long, hf),
                         __ATOMIC_RELAXED, __HIP_MEMORY_SCOPE_AGENT);
    }

    __syncthreads();  // [1] implicit vmcnt(0): all sc1 stores LLC-acked

    // single-lane arrival counter: add then poll SAME lane (deadlock-free)
    if (tid == 0) {
      int* c = &cnt[g * T_SZ + s];
      __hip_atomic_fetch_add(c, 1, __ATOMIC_RELAXED, __HIP_MEMORY_SCOPE_AGENT);
      while (__hip_atomic_load(c, __ATOMIC_RELAXED, __HIP_MEMORY_SCOPE_AGENT) < NS)
        __builtin_amdgcn_s_sleep(1);
    }
    __syncthreads();  // [2] peers' step-s data known visible at LLC

    // x_in prefetch for s+1 (in-bounds for all b; harmless garbage at s=T-1)
    xin = *(const float4*)seqp;

    // gather 3 peer slices (relaxed agent 8B loads) into hs[nxt]
#pragma unroll
    for (int p = 0; p < 3; ++p) {
      const int ps = (slice + 1 + p) & 3;
      const f16* src = ex + ((size_t)(cur * NG + g) * NS + ps) * EXB + gmr * SN + gc4;
      unsigned long long bits =
          __hip_atomic_load((const unsigned long long*)src, __ATOMIC_RELAXED, __HIP_MEMORY_SCOPE_AGENT);
      f16x4 pv = __builtin_bit_cast(f16x4, bits);
      const int e = (gmr * H_SZ + ps * SN + gc4) ^ ((gmr & 7) << 3);
      *(f16x4*)&hs[nxt][e] = pv;
    }
    __syncthreads();  // [3] hs[nxt] complete for step s+1
  }

  float4 hv;
  hv.x = hreg[0]; hv.y = hreg[1]; hv.z = hreg[2]; hv.w = hreg[3];
  *(float4*)(h_last + (size_t)b * H_SZ + j0) = hv;
}

extern "C" void kernel_launch(void* const* d_in, const int* in_sizes, int n_in,
                              void* d_out, int out_size, void* d_ws, size_t ws_size,
                              hipStream_t stream) {
  const float* x     = (const float*)d_in[0];
  const float* hin   = (const float*)d_in[1];
  const float* tau   = (const float*)d_in[2];
  const float* Win_w = (const float*)d_in[3];
  const float* Win_b = (const float*)d_in[4];
  const float* Wrec  = (const float*)d_in[5];

  float* out    = (float*)d_out;
  float* seq    = out;
  float* h_last = out + (size_t)B_SZ * T_SZ * H_SZ;

  int*   cnt  = (int*)d_ws;                                    // 16 KB
  f16*   ex   = (f16*)((char*)d_ws + 65536);                   // 256 KB
  float* WTin = (float*)((char*)d_ws + 65536 + 262144);        // 256 KB

  hipMemsetAsync(cnt, 0, NG * T_SZ * sizeof(int), stream);

  dim3 blk(256);
  transpose_k<<<dim3(D_SZ / 32, H_SZ / 32), blk, 0, stream>>>(Win_w, WTin, H_SZ, D_SZ);
  input_proj_k<<<(B_SZ * T_SZ) / 32, blk, 0, stream>>>(x, WTin, Win_b, seq);
  ltc_rec_mfma<<<NG * NS, 512, 0, stream>>>(seq, h_last, hin, tau, Wrec, cnt, ex);
}